// Round 2
// baseline (94364.838 us; speedup 1.0000x reference)
//
#include <hip/hip_runtime.h>

// ======================= constants =======================
static constexpr int NBLK = 256;            // cooperative grid (1 block/CU)
static constexpr int NTHR = 512;
static constexpr size_t HB = (size_t)512 * 128;     // one (feature,batch) plane (elements)

// ======================= workspace layout (bytes) =======================
static constexpr size_t OFF_ENC    = 0;            // bf16, swizzled [128 b][4 lb][64 r][128 cb][8 e]
static constexpr size_t OFF_WIHFT  = 67108864;     // f32 [128][2048]
static constexpr size_t OFF_WIHBT  = 68157440;
static constexpr size_t OFF_XDEC   = 69206016;     // dec_Wih cols 0..127 ^T  [128][2048]
static constexpr size_t OFF_WATTNT = 70254592;     // f32 [1024][512]
static constexpr size_t OFF_HENC   = 72351744;     // [2dir][2par][512][128]
static constexpr size_t OFF_CENC   = 73400320;     // [2dir][512][128]
static constexpr size_t OFF_HDEC   = 73924608;     // [2par][512][128]
static constexpr size_t OFF_CDEC   = 74448896;     // [512][128]
static constexpr size_t OFF_TOUT   = 74711040;     // [2par][512][128]
static constexpr size_t OFF_U      = 75235328;     // [1024][128]
static constexpr size_t OFF_CTX    = 75759616;     // [1024][128]
static constexpr size_t OFF_SC     = 76283904;     // [2 par][128][256] scores
static constexpr size_t OFF_MD     = 76546048;     // [2 par][384]: M,D,pgen
static constexpr size_t OFF_BAR    = 76550144;     // barrier state (8KB)

// ======================= smem layout (bytes) =======================
static constexpr int SM_TILE = 0;        // 131072: 64 rows x 1024 bf16 (swizzled uint4 blocks)
static constexpr int SM_U    = 131072;   // 1032 f32 (padded)
static constexpr int SM_SCP  = 135232;   // [64][9] f32
static constexpr int SM_PLDS = 137536;   // [64] f32
static constexpr int SM_BC   = 137792;   // [2] f32
static constexpr int SM_RED  = 137824;   // [8] f32
static constexpr int SM_PVP  = 137856;   // [3][1024] f32
static constexpr int SM_SIZE = 150208;

// ======================= params =======================
struct KP {
  const int* C_idx; const int* E_idx; const unsigned char* C_pad;
  const float* eWihF; const float* eWhhF; const float* ebF;
  const float* eWihB; const float* eWhhB; const float* ebB;
  const float* dWih;  const float* dWhh;  const float* db;
  const float* Wh; const float* Wc; const float* Wattn; const float* Wout; const float* Wvoc;
  const float* pgc; const float* pgi; const float* pgh; const float* pgcc; const float* pgb;
  char* wsb; float* out;
};

// ======================= helpers =======================
__device__ __forceinline__ float sigm(float x) { return 1.f / (1.f + expf(-x)); }
__device__ __forceinline__ unsigned short f2bf(float f) {
  unsigned u = __float_as_uint(f);
  u += 0x7fffu + ((u >> 16) & 1u);
  return (unsigned short)(u >> 16);
}
__device__ __forceinline__ float bfl(unsigned w) { return __uint_as_float(w << 16); }
__device__ __forceinline__ float bfh(unsigned w) { return __uint_as_float(w & 0xffff0000u); }

// Two-level grid barrier: 16 groups of 16 blocks, device-scope atomics.
// bar[0]=root cnt, bar[32]=generation, bar[64+g*32]=group cnts (each own line).
__device__ __forceinline__ void gbar(int* bar, int bid) {
  __syncthreads();
  if (threadIdx.x == 0) {
    __threadfence();   // release all ws writes before arriving
    int* gen = bar + 32;
    int g = __hip_atomic_load(gen, __ATOMIC_RELAXED, __HIP_MEMORY_SCOPE_AGENT);
    int* gc = bar + 64 + (bid >> 4) * 32;
    if (__hip_atomic_fetch_add(gc, 1, __ATOMIC_ACQ_REL, __HIP_MEMORY_SCOPE_AGENT) == 15) {
      __hip_atomic_store(gc, 0, __ATOMIC_RELAXED, __HIP_MEMORY_SCOPE_AGENT);
      if (__hip_atomic_fetch_add(bar, 1, __ATOMIC_ACQ_REL, __HIP_MEMORY_SCOPE_AGENT) == 15) {
        __hip_atomic_store(bar, 0, __ATOMIC_RELAXED, __HIP_MEMORY_SCOPE_AGENT);
        __hip_atomic_store(gen, g + 1, __ATOMIC_RELEASE, __HIP_MEMORY_SCOPE_AGENT);
      }
    }
    while (__hip_atomic_load(gen, __ATOMIC_ACQUIRE, __HIP_MEMORY_SCOPE_AGENT) == g)
      __builtin_amdgcn_s_sleep(2);
    __threadfence();   // acquire side
  }
  __syncthreads();
}

// ======================= phases =======================
__device__ void pre_phase(const KP& P, int bid, int tau) {
  float* WT_F = (float*)(P.wsb + OFF_WIHFT);
  float* WT_B = (float*)(P.wsb + OFF_WIHBT);
  float* XD   = (float*)(P.wsb + OFF_XDEC);
  float* WAT  = (float*)(P.wsb + OFF_WATTNT);
  int i0 = bid * NTHR + tau;
  int stride = NBLK * NTHR;
  for (int x = i0; x < 128 * 2048; x += stride) {
    int v = x >> 11, n = x & 2047;
    WT_F[x] = P.eWihF[n * 128 + v];
    WT_B[x] = P.eWihB[n * 128 + v];
    XD[x]   = P.dWih[n * 640 + v];
  }
  for (int x = i0; x < 1024 * 512; x += stride) {
    int j = x >> 9, i2 = x & 511;
    WAT[x] = P.Wattn[i2 * 1024 + j];
  }
}

__device__ void enc_phase(const KP& P, int bid, int tau, int t) {
  char* wsb = P.wsb;
  int p = bid * NTHR + tau;      // 2dir * 512j * 128b
  int b = p & 127;
  int j = (p >> 7) & 511;
  int dir = p >> 16;
  int jj = __builtin_amdgcn_readfirstlane(j);
  int dd = __builtin_amdgcn_readfirstlane(dir);
  const float* Whh  = dd ? P.eWhhB : P.eWhhF;
  const float* bias = dd ? P.ebB : P.ebF;
  const float* WihT = (const float*)(wsb + (dd ? OFF_WIHBT : OFF_WIHFT));
  int l = dd ? (255 - t) : t;
  int cidx = P.C_idx[b * 256 + l];
  int par = t & 1;
  const float* hp = (const float*)(wsb + OFF_HENC) + (size_t)(dir * 2 + (par ^ 1)) * HB + b;

  const float* w0 = Whh + (size_t)jj * 512;
  const float* w1 = Whh + (size_t)(512 + jj) * 512;
  const float* w2 = Whh + (size_t)(1024 + jj) * 512;
  const float* w3 = Whh + (size_t)(1536 + jj) * 512;
  float a0 = bias[jj]        + WihT[(size_t)cidx * 2048 + jj];
  float a1 = bias[512 + jj]  + WihT[(size_t)cidx * 2048 + 512 + jj];
  float a2 = bias[1024 + jj] + WihT[(size_t)cidx * 2048 + 1024 + jj];
  float a3 = bias[1536 + jj] + WihT[(size_t)cidx * 2048 + 1536 + jj];
  for (int k = 0; k < 512; k += 4) {
    float4 W0 = *(const float4*)(w0 + k);
    float4 W1 = *(const float4*)(w1 + k);
    float4 W2 = *(const float4*)(w2 + k);
    float4 W3 = *(const float4*)(w3 + k);
    float h0 = hp[(size_t)k * 128], h1 = hp[(size_t)(k + 1) * 128];
    float h2 = hp[(size_t)(k + 2) * 128], h3 = hp[(size_t)(k + 3) * 128];
    a0 += W0.x * h0 + W0.y * h1 + W0.z * h2 + W0.w * h3;
    a1 += W1.x * h0 + W1.y * h1 + W1.z * h2 + W1.w * h3;
    a2 += W2.x * h0 + W2.y * h1 + W2.z * h2 + W2.w * h3;
    a3 += W3.x * h0 + W3.y * h1 + W3.z * h2 + W3.w * h3;
  }
  float ig = sigm(a0), fg = sigm(a1), gg = tanhf(a2), og = sigm(a3);
  float* cp = (float*)(wsb + OFF_CENC) + (size_t)dir * HB + (size_t)j * 128 + b;
  float c = fg * (*cp) + ig * gg;
  *cp = c;
  float h = og * tanhf(c);
  ((float*)(wsb + OFF_HENC))[(size_t)(dir * 2 + par) * HB + (size_t)j * 128 + b] = h;
  // swizzled bf16 store: f=dir*512+j; within b-slice: [lb][r][cb^(r&7)][e]
  int f = dir * 512 + j;
  int cb = f >> 3, e = f & 7;
  int r = l & 63, lbt = l >> 6;
  size_t idx = (size_t)b * 262144 + (size_t)lbt * 65536 + ((size_t)r << 10) + ((size_t)(cb ^ (r & 7)) << 3) + e;
  ((unsigned short*)(wsb + OFF_ENC))[idx] = f2bf(h);
}

__device__ void h0c0_phase(const KP& P, int bid, int tau) {
  char* wsb = P.wsb;
  int p = bid * NTHR + tau;      // 2sel * 512n * 128b
  int b = p & 127;
  int n = (p >> 7) & 511;
  int sel = p >> 16;
  int nn = __builtin_amdgcn_readfirstlane(n);
  int ss = __builtin_amdgcn_readfirstlane(sel);
  const float* W = (ss ? P.Wc : P.Wh) + (size_t)nn * 1024;
  // sel=0 (h0): final hidden states (HENC planes 1 and 3, par=1)
  // sel=1 (c0): final CELL states (CENC planes 0 and 1)   [bug fix vs round 1]
  const float* af = (const float*)(wsb + (ss ? OFF_CENC : OFF_HENC + HB * 4)) + b;
  const float* ab = (const float*)(wsb + (ss ? OFF_CENC + HB * 4 : OFF_HENC + 3 * HB * 4)) + b;
  float acc = 0.f;
  for (int k = 0; k < 512; k += 4) {
    float4 Wa = *(const float4*)(W + k);
    float4 Wb = *(const float4*)(W + 512 + k);
    acc += Wa.x * af[(size_t)k * 128] + Wa.y * af[(size_t)(k + 1) * 128]
         + Wa.z * af[(size_t)(k + 2) * 128] + Wa.w * af[(size_t)(k + 3) * 128];
    acc += Wb.x * ab[(size_t)k * 128] + Wb.y * ab[(size_t)(k + 1) * 128]
         + Wb.z * ab[(size_t)(k + 2) * 128] + Wb.w * ab[(size_t)(k + 3) * 128];
  }
  float* dst = (float*)(wsb + (ss ? OFF_CDEC : OFF_HDEC));
  dst[(size_t)n * 128 + b] = acc;
}

__device__ void dgates_phase(const KP& P, char* smem, int bid, int tau, int t) {
  char* wsb = P.wsb;
  float (*part)[256] = (float(*)[256])smem;
  int kh = tau >> 8, q = tau & 255;
  int pp = bid * 256 + q;          // 512j * 128b
  int b = pp & 127, j = pp >> 7;
  int jj = __builtin_amdgcn_readfirstlane(j);
  int pr = t & 1;
  float a0 = 0.f, a1 = 0.f, a2 = 0.f, a3 = 0.f;
  if (kh == 0) {   // prev_out half (dec_Wih cols 128..639)
    const float* w0 = P.dWih + (size_t)jj * 640 + 128;
    const float* w1 = P.dWih + (size_t)(512 + jj) * 640 + 128;
    const float* w2 = P.dWih + (size_t)(1024 + jj) * 640 + 128;
    const float* w3 = P.dWih + (size_t)(1536 + jj) * 640 + 128;
    const float* po = (const float*)(wsb + OFF_TOUT) + (size_t)pr * HB + b;
    for (int k = 0; k < 512; k += 4) {
      float4 W0 = *(const float4*)(w0 + k);
      float4 W1 = *(const float4*)(w1 + k);
      float4 W2 = *(const float4*)(w2 + k);
      float4 W3 = *(const float4*)(w3 + k);
      float h0 = po[(size_t)k * 128], h1 = po[(size_t)(k + 1) * 128];
      float h2 = po[(size_t)(k + 2) * 128], h3 = po[(size_t)(k + 3) * 128];
      a0 += W0.x * h0 + W0.y * h1 + W0.z * h2 + W0.w * h3;
      a1 += W1.x * h0 + W1.y * h1 + W1.z * h2 + W1.w * h3;
      a2 += W2.x * h0 + W2.y * h1 + W2.z * h2 + W2.w * h3;
      a3 += W3.x * h0 + W3.y * h1 + W3.z * h2 + W3.w * h3;
    }
  } else {         // h half (dec_Whh)
    const float* w0 = P.dWhh + (size_t)jj * 512;
    const float* w1 = P.dWhh + (size_t)(512 + jj) * 512;
    const float* w2 = P.dWhh + (size_t)(1024 + jj) * 512;
    const float* w3 = P.dWhh + (size_t)(1536 + jj) * 512;
    const float* hp = (const float*)(wsb + OFF_HDEC) + (size_t)pr * HB + b;
    for (int k = 0; k < 512; k += 4) {
      float4 W0 = *(const float4*)(w0 + k);
      float4 W1 = *(const float4*)(w1 + k);
      float4 W2 = *(const float4*)(w2 + k);
      float4 W3 = *(const float4*)(w3 + k);
      float h0 = hp[(size_t)k * 128], h1 = hp[(size_t)(k + 1) * 128];
      float h2 = hp[(size_t)(k + 2) * 128], h3 = hp[(size_t)(k + 3) * 128];
      a0 += W0.x * h0 + W0.y * h1 + W0.z * h2 + W0.w * h3;
      a1 += W1.x * h0 + W1.y * h1 + W1.z * h2 + W1.w * h3;
      a2 += W2.x * h0 + W2.y * h1 + W2.z * h2 + W2.w * h3;
      a3 += W3.x * h0 + W3.y * h1 + W3.z * h2 + W3.w * h3;
    }
    part[0][q] = a0; part[1][q] = a1; part[2][q] = a2; part[3][q] = a3;
  }
  __syncthreads();
  if (kh == 0) {
    int xid = P.E_idx[b * 257 + t];
    const float* xg = (const float*)(wsb + OFF_XDEC) + (size_t)xid * 2048;
    float g0 = a0 + part[0][q] + P.db[jj]        + xg[jj];
    float g1 = a1 + part[1][q] + P.db[512 + jj]  + xg[512 + jj];
    float g2 = a2 + part[2][q] + P.db[1024 + jj] + xg[1024 + jj];
    float g3 = a3 + part[3][q] + P.db[1536 + jj] + xg[1536 + jj];
    float ig = sigm(g0), fg = sigm(g1), gg = tanhf(g2), og = sigm(g3);
    float* cp = (float*)(wsb + OFF_CDEC) + (size_t)j * 128 + b;
    float c = fg * (*cp) + ig * gg;
    *cp = c;
    ((float*)(wsb + OFF_HDEC))[(size_t)(pr ^ 1) * HB + (size_t)j * 128 + b] = og * tanhf(c);
  }
}

__device__ void u_phase(const KP& P, int bid, int tau, int t) {
  char* wsb = P.wsb;
  int p = bid * NTHR + tau;   // 1024j * 128b
  int b = p & 127, j = p >> 7;
  int jj = __builtin_amdgcn_readfirstlane(j);
  const float* w = (const float*)(wsb + OFF_WATTNT) + (size_t)jj * 512;
  const float* hp = (const float*)(wsb + OFF_HDEC) + (size_t)((t & 1) ^ 1) * HB + b;
  float acc = 0.f;
  for (int k = 0; k < 512; k += 4) {
    float4 W = *(const float4*)(w + k);
    acc += W.x * hp[(size_t)k * 128] + W.y * hp[(size_t)(k + 1) * 128]
         + W.z * hp[(size_t)(k + 2) * 128] + W.w * hp[(size_t)(k + 3) * 128];
  }
  ((float*)(wsb + OFF_U))[(size_t)j * 128 + b] = acc;
}

__device__ void attn_phase(const KP& P, char* smem, int b, int tau, int t) {
  char* wsb = P.wsb;
  unsigned short* tile = (unsigned short*)(smem + SM_TILE);
  uint4* tile4 = (uint4*)(smem + SM_TILE);
  float* u_lds = (float*)(smem + SM_U);
  float (*scp)[9] = (float(*)[9])(smem + SM_SCP);
  float* p_lds = (float*)(smem + SM_PLDS);
  float* bc = (float*)(smem + SM_BC);
  float* red = (float*)(smem + SM_RED);
  float* pvp = (float*)(smem + SM_PVP);
  int pr = t & 1;
  const float* U = (const float*)(wsb + OFF_U);
  u_lds[tau + (tau >> 7)] = U[(size_t)tau * 128 + b];
  { int x2 = tau + 512; u_lds[x2 + (x2 >> 7)] = U[(size_t)x2 * 128 + b]; }
  float M = -3.0e38f, D = 0.f;
  float acc[8];
#pragma unroll
  for (int e = 0; e < 8; ++e) acc[e] = 0.f;
  const uint4* encb = (const uint4*)(wsb + OFF_ENC + (size_t)b * 524288);
  float* SCp = (float*)(wsb + OFF_SC) + (size_t)pr * 128 * 256;
  int l = tau >> 3, seg = tau & 7;      // scores mapping
  int fg = tau & 127, rs = tau >> 7;    // PV mapping
  for (int lb = 0; lb < 4; ++lb) {
    const uint4* src = encb + (size_t)lb * 8192;
#pragma unroll
    for (int it = 0; it < 16; ++it) {
      int fl = it * 512 + tau;
      tile4[fl] = src[fl];               // enc pre-swizzled: linear copy
    }
    __syncthreads();
    // scores partials
    float sacc = 0.f;
#pragma unroll
    for (int ibv = 0; ibv < 16; ++ibv) {
      int blk = (seg * 16 + ibv) ^ (l & 7);
      const uint4 wv = tile4[(l << 7) + blk];
      const float* up = &u_lds[seg * 128 + ibv * 8 + seg];
      sacc += bfl(wv.x) * up[0] + bfh(wv.x) * up[1];
      sacc += bfl(wv.y) * up[2] + bfh(wv.y) * up[3];
      sacc += bfl(wv.z) * up[4] + bfh(wv.z) * up[5];
      sacc += bfl(wv.w) * up[6] + bfh(wv.w) * up[7];
    }
    scp[l][seg] = sacc;
    __syncthreads();
    if (tau < 64) {
      float s = scp[tau][0] + scp[tau][1] + scp[tau][2] + scp[tau][3]
              + scp[tau][4] + scp[tau][5] + scp[tau][6] + scp[tau][7];
      int gl = lb * 64 + tau;
      if (P.C_pad[b * 256 + gl]) s = -3.0e38f;
      SCp[b * 256 + gl] = s;
      float m = s;
      for (int o = 32; o; o >>= 1) m = fmaxf(m, __shfl_xor(m, o));
      float Mn = fmaxf(M, m);
      float pv = expf(s - Mn);
      p_lds[tau] = pv;
      float ds = pv;
      for (int o = 32; o; o >>= 1) ds += __shfl_xor(ds, o);
      if (tau == 0) { bc[0] = m; bc[1] = ds; }
    }
    __syncthreads();
    float Mn = fmaxf(M, bc[0]);
    float scale = expf(M - Mn);
    D = D * scale + bc[1];
    M = Mn;
#pragma unroll
    for (int e = 0; e < 8; ++e) acc[e] *= scale;
    int base = rs * 16;
#pragma unroll
    for (int l2i = 0; l2i < 16; ++l2i) {
      int l2 = base + l2i;
      float pv = p_lds[l2];
      const uint4 wv = tile4[(l2 << 7) + (fg ^ (l2 & 7))];
      acc[0] += pv * bfl(wv.x); acc[1] += pv * bfh(wv.x);
      acc[2] += pv * bfl(wv.y); acc[3] += pv * bfh(wv.y);
      acc[4] += pv * bfl(wv.z); acc[5] += pv * bfh(wv.z);
      acc[6] += pv * bfl(wv.w); acc[7] += pv * bfh(wv.w);
    }
    __syncthreads();
  }
  // cross-slice reduce + normalize + CTX store
  if (rs > 0) {
    float4* dst = (float4*)(pvp + (rs - 1) * 1024 + fg * 8);
    dst[0] = make_float4(acc[0], acc[1], acc[2], acc[3]);
    dst[1] = make_float4(acc[4], acc[5], acc[6], acc[7]);
  }
  __syncthreads();
  if (rs == 0) {
    float inv = 1.f / D;
    float* CTX = (float*)(wsb + OFF_CTX);
    float4 q0 = ((float4*)(pvp + fg * 8))[0],        q1 = ((float4*)(pvp + fg * 8))[1];
    float4 r0 = ((float4*)(pvp + 1024 + fg * 8))[0], r1 = ((float4*)(pvp + 1024 + fg * 8))[1];
    float4 s0 = ((float4*)(pvp + 2048 + fg * 8))[0], s1 = ((float4*)(pvp + 2048 + fg * 8))[1];
    float x0 = (acc[0] + q0.x + r0.x + s0.x) * inv;
    float x1 = (acc[1] + q0.y + r0.y + s0.y) * inv;
    float x2 = (acc[2] + q0.z + r0.z + s0.z) * inv;
    float x3 = (acc[3] + q0.w + r0.w + s0.w) * inv;
    float x4 = (acc[4] + q1.x + r1.x + s1.x) * inv;
    float x5 = (acc[5] + q1.y + r1.y + s1.y) * inv;
    float x6 = (acc[6] + q1.z + r1.z + s1.z) * inv;
    float x7 = (acc[7] + q1.w + r1.w + s1.w) * inv;
    ((float4*)(pvp + fg * 8))[0] = make_float4(x0, x1, x2, x3);
    ((float4*)(pvp + fg * 8))[1] = make_float4(x4, x5, x6, x7);
    int f = fg * 8;
    CTX[(size_t)(f + 0) * 128 + b] = x0; CTX[(size_t)(f + 1) * 128 + b] = x1;
    CTX[(size_t)(f + 2) * 128 + b] = x2; CTX[(size_t)(f + 3) * 128 + b] = x3;
    CTX[(size_t)(f + 4) * 128 + b] = x4; CTX[(size_t)(f + 5) * 128 + b] = x5;
    CTX[(size_t)(f + 6) * 128 + b] = x6; CTX[(size_t)(f + 7) * 128 + b] = x7;
  }
  __syncthreads();
  // p_gen
  const float* cl = pvp;   // normalized ctx [1024]
  float pp = cl[tau] * P.pgc[tau] + cl[tau + 512] * P.pgc[tau + 512];
  pp += ((const float*)(wsb + OFF_HDEC))[(size_t)(pr ^ 1) * HB + (size_t)tau * 128 + b] * P.pgh[tau];
  pp += ((const float*)(wsb + OFF_CDEC))[(size_t)tau * 128 + b] * P.pgcc[tau];
  pp += ((const float*)(wsb + OFF_TOUT))[(size_t)pr * HB + (size_t)tau * 128 + b] * P.pgi[128 + tau];
  for (int o = 32; o; o >>= 1) pp += __shfl_xor(pp, o);
  if ((tau & 63) == 0) red[tau >> 6] = pp;
  __syncthreads();
  if (tau == 0) {
    float s = red[0] + red[1] + red[2] + red[3] + red[4] + red[5] + red[6] + red[7];
    int xid = P.E_idx[b * 257 + t];
    s += P.pgi[xid] + P.pgb[0];
    float* MDp = (float*)(wsb + OFF_MD) + (size_t)pr * 384;
    MDp[256 + b] = sigm(s);
    MDp[b] = M;
    MDp[128 + b] = D;
  }
}

// vocab softmax at target + copy mass + nll for step t-1 (t in [1,256])
__device__ void s4_body(const KP& P, char* smem, int b, int t) {
  char* wsb = P.wsb;
  float* to = (float*)smem;                       // 516
  float (*lgp)[4] = (float(*)[4])(smem + 2064);   // [128][4]
  float* lg = (float*)(smem + 4112);              // 128
  float* red2 = (float*)(smem + 4624);            // 8
  float* mx_s = (float*)(smem + 4656);            // 2
  int tau = threadIdx.x;
  const float* TO = (const float*)(wsb + OFF_TOUT) + (size_t)(t & 1) * HB;
  to[tau + (tau >> 7)] = TO[(size_t)tau * 128 + b];
  __syncthreads();
  int v = tau >> 2, seg = tau & 3;
  const float* wv = P.Wvoc + (size_t)v * 512 + seg * 128;
  const float* tp = &to[seg * 128 + seg];
  float part = 0.f;
#pragma unroll 8
  for (int i = 0; i < 128; ++i) part += tp[i] * wv[i];
  lgp[v][seg] = part;
  __syncthreads();
  if (tau < 128) lg[tau] = lgp[tau][0] + lgp[tau][1] + lgp[tau][2] + lgp[tau][3];
  __syncthreads();
  if (tau < 64) {
    float m2 = fmaxf(lg[tau], lg[tau + 64]);
    for (int o = 32; o; o >>= 1) m2 = fmaxf(m2, __shfl_xor(m2, o));
    float e = expf(lg[tau] - m2) + expf(lg[tau + 64] - m2);
    for (int o = 32; o; o >>= 1) e += __shfl_xor(e, o);
    if (tau == 0) { mx_s[0] = m2; mx_s[1] = e; }
  }
  int pr1 = (t - 1) & 1;
  const float* MDp = (const float*)(wsb + OFF_MD) + (size_t)pr1 * 384;
  const float* SCp = (const float*)(wsb + OFF_SC) + (size_t)pr1 * 128 * 256;
  float Mb = MDp[b], Db = MDp[128 + b], pg = MDp[256 + b];
  int tgt = P.E_idx[b * 257 + t];
  float cm = 0.f;
  if (tau < 256) {
    float s = SCp[b * 256 + tau];
    if (P.C_idx[b * 256 + tau] == tgt) cm = expf(s - Mb);
  }
  for (int o = 32; o; o >>= 1) cm += __shfl_xor(cm, o);
  if ((tau & 63) == 0) red2[tau >> 6] = cm;
  __syncthreads();
  if (tau == 0) {
    float mass = (red2[0] + red2[1] + red2[2] + red2[3]) / Db;
    float gen_tgt = expf(lg[tgt] - mx_s[0]) / mx_s[1];
    float prob = pg * gen_tgt + (1.f - pg) * mass;
    P.out[b * 256 + (t - 1)] = (tgt == 0) ? 0.f : -logf(prob);
  }
  __syncthreads();
}

__device__ void wout_phase(const KP& P, char* smem, int bid, int tau, int t) {
  char* wsb = P.wsb;
  float* part = (float*)smem;
  int kh = tau >> 8, q = tau & 255;
  int pp = bid * 256 + q;     // 512n * 128b
  int b = pp & 127, n = pp >> 7;
  int nn = __builtin_amdgcn_readfirstlane(n);
  int pr = t & 1;
  float acc = 0.f;
  if (kh == 0) {
    const float* w = P.Wout + (size_t)nn * 1536;
    const float* hp = (const float*)(wsb + OFF_HDEC) + (size_t)(pr ^ 1) * HB + b;
    for (int k = 0; k < 512; k += 4) {
      float4 W = *(const float4*)(w + k);
      acc += W.x * hp[(size_t)k * 128] + W.y * hp[(size_t)(k + 1) * 128]
           + W.z * hp[(size_t)(k + 2) * 128] + W.w * hp[(size_t)(k + 3) * 128];
    }
  } else {
    const float* w = P.Wout + (size_t)nn * 1536 + 512;
    const float* cp = (const float*)(wsb + OFF_CTX) + b;
    for (int k = 0; k < 1024; k += 4) {
      float4 W = *(const float4*)(w + k);
      acc += W.x * cp[(size_t)k * 128] + W.y * cp[(size_t)(k + 1) * 128]
           + W.z * cp[(size_t)(k + 2) * 128] + W.w * cp[(size_t)(k + 3) * 128];
    }
    part[q] = acc;
  }
  __syncthreads();
  if (kh == 0) {
    float s = acc + part[q];
    ((float*)(wsb + OFF_TOUT))[(size_t)(pr ^ 1) * HB + (size_t)n * 128 + b] = tanhf(s);
  }
}

// ======================= the persistent kernel =======================
__global__ void __launch_bounds__(NTHR) k_all(KP P) {
  __shared__ __align__(16) char smem[SM_SIZE];
  const int bid = blockIdx.x;
  const int tau = threadIdx.x;
  int* bar = (int*)(P.wsb + OFF_BAR);

  pre_phase(P, bid, tau);
  gbar(bar, bid);

  for (int t = 0; t < 256; ++t) {
    enc_phase(P, bid, tau, t);
    gbar(bar, bid);
  }
  h0c0_phase(P, bid, tau);
  gbar(bar, bid);

  for (int t = 0; t < 256; ++t) {
    dgates_phase(P, smem, bid, tau, t);
    gbar(bar, bid);
    u_phase(P, bid, tau, t);
    gbar(bar, bid);
    if (bid < 128) attn_phase(P, smem, bid, tau, t);
    else if (t > 0) s4_body(P, smem, bid - 128, t);
    gbar(bar, bid);
    wout_phase(P, smem, bid, tau, t);
    gbar(bar, bid);
  }
  if (bid < 128) s4_body(P, smem, bid, 256);
}

// ======================= host =======================
extern "C" void kernel_launch(void* const* d_in, const int* in_sizes, int n_in,
                              void* d_out, int out_size, void* d_ws, size_t ws_size,
                              hipStream_t stream) {
  (void)in_sizes; (void)n_in; (void)out_size; (void)ws_size;
  KP P;
  P.C_idx = (const int*)d_in[0];
  P.E_idx = (const int*)d_in[1];
  P.C_pad = (const unsigned char*)d_in[2];
  P.eWihF = (const float*)d_in[3];
  P.eWhhF = (const float*)d_in[4];
  P.ebF   = (const float*)d_in[5];
  P.eWihB = (const float*)d_in[6];
  P.eWhhB = (const float*)d_in[7];
  P.ebB   = (const float*)d_in[8];
  P.dWih  = (const float*)d_in[9];
  P.dWhh  = (const float*)d_in[10];
  P.db    = (const float*)d_in[11];
  P.Wh    = (const float*)d_in[12];
  P.Wc    = (const float*)d_in[13];
  P.Wattn = (const float*)d_in[14];
  P.Wout  = (const float*)d_in[15];
  P.Wvoc  = (const float*)d_in[16];
  P.pgc   = (const float*)d_in[17];
  P.pgi   = (const float*)d_in[18];
  P.pgh   = (const float*)d_in[19];
  P.pgcc  = (const float*)d_in[20];
  P.pgb   = (const float*)d_in[21];
  P.wsb   = (char*)d_ws;
  P.out   = (float*)d_out;

  // zero recurrent init state + barrier
  hipMemsetAsync((char*)d_ws + OFF_HENC, 0, 6 * HB * 4, stream);   // h_enc(4 planes)+c_enc(2)
  hipMemsetAsync((char*)d_ws + OFF_TOUT, 0, 2 * HB * 4, stream);   // prev_out both parities
  hipMemsetAsync((char*)d_ws + OFF_BAR, 0, 8192, stream);          // barrier counters/gen

  void* args[] = { &P };
  hipLaunchCooperativeKernel((const void*)k_all, dim3(NBLK), dim3(NTHR), args, 0, stream);
}

// Round 3
// 63308.319 us; speedup vs baseline: 1.4906x; 1.4906x over previous
//
#include <hip/hip_runtime.h>

// ======================= ws layout (bytes) =======================
// proven ws high-water from round 1/2: 76,558,336 — stay below.
static constexpr size_t OFF_ENC  = 0;          // u16 enc [128 b][256 l][1024 f]  (64 MiB)
static constexpr size_t OFF_HFIN = 67108864;   // f32 [128][2][512]
static constexpr size_t OFF_CFIN = 67633152;   // f32 [128][2][512]
static constexpr size_t OFF_OVL  = 68157440;   // overlay region (<= 8.4 MB)
// encoder-phase overlay (ushort element offsets from OFF_OVL):
//   WHHE[dir] : dir*1048576      [k2 256][j 512][8]   (2 MiB each)
//   WIHT[dir] : 2097152 + dir*262144  [v 128][j 512][4]
// decoder-phase overlay (ushort element offsets):
//   DWIH 0         [k2 256][j 512][8]
//   DWHH 1048576   [k2 256][j 512][8]
//   WATT 2097152   [i4 128][o 1024][4]
//   WOUT 2621440   [i4 384][j 512][4]
//   WVOC 3407872   [i4 128][v 128][4]
//   XDEC 3473408   [v 128][j 512][4]
// overlay end: 68157440 + 7471104*2? (ushort counts) -> bytes 7,471,104 -> 75,628,544  OK

// ======================= helpers =======================
__device__ __forceinline__ float sigm(float x) { return 1.f / (1.f + expf(-x)); }
__device__ __forceinline__ unsigned short f2bf(float f) {
  unsigned u = __float_as_uint(f);
  u += 0x7fffu + ((u >> 16) & 1u);
  return (unsigned short)(u >> 16);
}
__device__ __forceinline__ float bfl(unsigned w) { return __uint_as_float(w << 16); }
__device__ __forceinline__ float bfh(unsigned w) { return __uint_as_float(w & 0xffff0000u); }
__device__ __forceinline__ float bf2f(unsigned short v) { return __uint_as_float(((unsigned)v) << 16); }

#if defined(__has_builtin)
#if __has_builtin(__builtin_amdgcn_fdot2_f32_bf16)
#define HAVE_DOT2BF 1
#endif
#endif

#ifdef HAVE_DOT2BF
typedef __bf16 bf2_t __attribute__((ext_vector_type(2)));
__device__ __forceinline__ float dot2bf(unsigned w, unsigned h, float acc) {
  return __builtin_amdgcn_fdot2_f32_bf16(__builtin_bit_cast(bf2_t, w),
                                         __builtin_bit_cast(bf2_t, h), acc, false);
}
#else
__device__ __forceinline__ float dot2bf(unsigned w, unsigned h, float acc) {
  return acc + bfl(w) * bfl(h) + bfh(w) * bfh(h);
}
#endif

// ======================= pre1: encoder weight packing =======================
__global__ __launch_bounds__(256) void k_pre1(const float* __restrict__ WhhF,
                                              const float* __restrict__ WhhB,
                                              const float* __restrict__ WihF,
                                              const float* __restrict__ WihB,
                                              char* __restrict__ wsb) {
  unsigned short* dst = (unsigned short*)(wsb + OFF_OVL);
  int id = blockIdx.x * 256 + threadIdx.x;
  int str = gridDim.x * 256;
  // WHHE: [dir][k2][j][8]  e = g*2+kk
  for (int x = id; x < 2097152; x += str) {
    int dir = x >> 20, r = x & 1048575;
    int e = r & 7, j = (r >> 3) & 511, k2 = r >> 12;
    int g = e >> 1, k = k2 * 2 + (e & 1);
    const float* W = dir ? WhhB : WhhF;
    dst[x] = f2bf(W[((size_t)g * 512 + j) * 512 + k]);
  }
  // WIHT: [dir][v][j][4]
  for (int x = id; x < 524288; x += str) {
    int dir = x >> 18, r = x & 262143;
    int g = r & 3, j = (r >> 2) & 511, v = r >> 11;
    const float* W = dir ? WihB : WihF;
    dst[2097152 + x] = f2bf(W[((size_t)g * 512 + j) * 128 + v]);
  }
}

// ======================= pre2: decoder weight packing =======================
__global__ __launch_bounds__(256) void k_pre2(const float* __restrict__ dWih,
                                              const float* __restrict__ dWhh,
                                              const float* __restrict__ Wattn,
                                              const float* __restrict__ Wout,
                                              const float* __restrict__ Wvoc,
                                              char* __restrict__ wsb) {
  unsigned short* dst = (unsigned short*)(wsb + OFF_OVL);
  int id = blockIdx.x * 256 + threadIdx.x;
  int str = gridDim.x * 256;
  for (int x = id; x < 1048576; x += str) {         // DWIH (prev_out cols 128..639)
    int e = x & 7, j = (x >> 3) & 511, k2 = x >> 12;
    int g = e >> 1, k = k2 * 2 + (e & 1);
    dst[x] = f2bf(dWih[((size_t)g * 512 + j) * 640 + 128 + k]);
  }
  for (int x = id; x < 1048576; x += str) {         // DWHH
    int e = x & 7, j = (x >> 3) & 511, k2 = x >> 12;
    int g = e >> 1, k = k2 * 2 + (e & 1);
    dst[1048576 + x] = f2bf(dWhh[((size_t)g * 512 + j) * 512 + k]);
  }
  for (int x = id; x < 524288; x += str) {          // WATT [i4][o][4]
    int e = x & 3, o = (x >> 2) & 1023, i4 = x >> 12;
    int i = i4 * 4 + e;
    dst[2097152 + x] = f2bf(Wattn[(size_t)i * 1024 + o]);
  }
  for (int x = id; x < 786432; x += str) {          // WOUT [i4][j][4]
    int e = x & 3, j = (x >> 2) & 511, i4 = x >> 11;
    int i = i4 * 4 + e;
    dst[2621440 + x] = f2bf(Wout[(size_t)j * 1536 + i]);
  }
  for (int x = id; x < 65536; x += str) {           // WVOC [i4][v][4]
    int e = x & 3, v = (x >> 2) & 127, i4 = x >> 9;
    int i = i4 * 4 + e;
    dst[3407872 + x] = f2bf(Wvoc[(size_t)v * 512 + i]);
  }
  for (int x = id; x < 262144; x += str) {          // XDEC [v][j][4]
    int g = x & 3, j = (x >> 2) & 511, v = x >> 11;
    dst[3473408 + x] = f2bf(dWih[((size_t)g * 512 + j) * 640 + v]);
  }
}

// ======================= encoder: one block per (b, dir) =======================
__global__ __launch_bounds__(512) void k_enc(const float* __restrict__ bF,
                                             const float* __restrict__ bB,
                                             const int* __restrict__ C_idx,
                                             char* __restrict__ wsb) {
  __shared__ __align__(16) unsigned short hbf[512];
  int bid = blockIdx.x;
  int b = bid & 127, dir = bid >> 7;
  int j = threadIdx.x;
  const unsigned short* WH = (const unsigned short*)(wsb + OFF_OVL) + (size_t)dir * 1048576;
  const unsigned short* WX = (const unsigned short*)(wsb + OFF_OVL) + 2097152 + (size_t)dir * 262144;
  const float* bias = dir ? bB : bF;
  float b0 = bias[j], b1 = bias[512 + j], b2 = bias[1024 + j], b3 = bias[1536 + j];
  unsigned short* encb = (unsigned short*)wsb + (size_t)b * 262144;
  const uint4* wp = (const uint4*)WH + j;
  float c = 0.f, h = 0.f;
  hbf[j] = 0;
  __syncthreads();
  for (int t = 0; t < 256; ++t) {
    int l = dir ? (255 - t) : t;
    int cidx = C_idx[b * 256 + l];
    uint2 xg = *(const uint2*)(WX + ((size_t)cidx * 512 + j) * 4);
    float a0 = b0 + bfl(xg.x), a1 = b1 + bfh(xg.x);
    float a2 = b2 + bfl(xg.y), a3 = b3 + bfh(xg.y);
    for (int k2 = 0; k2 < 256; ++k2) {
      uint4 w = wp[(size_t)k2 * 512];
      unsigned hp = *(const unsigned*)((const char*)hbf + k2 * 4);
      a0 = dot2bf(w.x, hp, a0);
      a1 = dot2bf(w.y, hp, a1);
      a2 = dot2bf(w.z, hp, a2);
      a3 = dot2bf(w.w, hp, a3);
    }
    float ig = sigm(a0), fg = sigm(a1), gg = tanhf(a2), og = sigm(a3);
    c = fg * c + ig * gg;
    h = og * tanhf(c);
    __syncthreads();                       // all hbf reads done
    unsigned short hb = f2bf(h);
    hbf[j] = hb;
    encb[(size_t)l * 1024 + dir * 512 + j] = hb;
    __syncthreads();                       // new hbf visible
  }
  ((float*)(wsb + OFF_HFIN))[((size_t)b * 2 + dir) * 512 + j] = h;
  ((float*)(wsb + OFF_CFIN))[((size_t)b * 2 + dir) * 512 + j] = c;
}

// ======================= decoder: one block per batch elem =======================
__global__ __launch_bounds__(1024, 4) void k_dec(
    const int* __restrict__ C_idx, const int* __restrict__ E_idx,
    const unsigned char* __restrict__ C_pad,
    const float* __restrict__ db, const float* __restrict__ Wh, const float* __restrict__ Wc,
    const float* __restrict__ pgc, const float* __restrict__ pgi,
    const float* __restrict__ pgh, const float* __restrict__ pgcc, const float* __restrict__ pgb,
    char* __restrict__ wsb, float* __restrict__ out) {
  __shared__ __align__(16) unsigned short inbf[1536];  // [0,512)=h bf16, [512,1536)=ctx bf16
  __shared__ __align__(16) unsigned short tobf[512];   // prev_out / t_out bf16
  __shared__ __align__(16) unsigned short ubf[1024];
  __shared__ float cst[512];
  __shared__ float hf32[512];
  __shared__ float ctxf[1024];
  __shared__ __align__(16) float part[2][512][4];      // 16 KiB, multi-use
  __shared__ float sc[256];
  __shared__ float pr[256];
  __shared__ float red[16];
  __shared__ float scal[4];
  __shared__ float lgf[128];

  int b = blockIdx.x;
  int tau = threadIdx.x;
  int lane = tau & 63;
  int wv = tau >> 6;

  const unsigned short* DWIH = (const unsigned short*)(wsb + OFF_OVL);
  const unsigned short* DWHH = DWIH + 1048576;
  const unsigned short* WATT = DWIH + 2097152;
  const unsigned short* WOUT = DWIH + 2621440;
  const unsigned short* WVOC = DWIH + 3407872;
  const unsigned short* XDEC = DWIH + 3473408;
  const unsigned short* encB = (const unsigned short*)wsb + (size_t)b * 262144;

  // ---- prologue: h0 = [hf;hb]@Wh^T, c0 = [cf;cb]@Wc^T ----
  {
    float* catH = &part[0][0][0];
    float* catC = catH + 1024;
    const float* HF = (const float*)(wsb + OFF_HFIN) + (size_t)b * 1024;
    const float* CF = (const float*)(wsb + OFF_CFIN) + (size_t)b * 1024;
    if (tau < 1024) { catH[tau] = HF[tau]; catC[tau] = CF[tau]; }
    __syncthreads();
    for (int oo = 0; oo < 64; ++oo) {
      int o = wv * 64 + oo;
      int sel = o >> 9, j = o & 511;
      const float* Wrow = (sel ? Wc : Wh) + (size_t)j * 1024;
      const float* inp = sel ? catC : catH;
      float a = 0.f;
      for (int p = 0; p < 4; ++p) {
        float4 wf = *(const float4*)(Wrow + p * 256 + lane * 4);
        float4 iv = *(const float4*)(inp + p * 256 + lane * 4);
        a += wf.x * iv.x + wf.y * iv.y + wf.z * iv.z + wf.w * iv.w;
      }
      for (int o2 = 32; o2; o2 >>= 1) a += __shfl_xor(a, o2);
      if (lane == 0) {
        if (sel == 0) { hf32[j] = a; inbf[j] = f2bf(a); }
        else cst[j] = a;
      }
    }
    if (tau < 512) tobf[tau] = 0;
    __syncthreads();
  }

  for (int t = 0; t < 256; ++t) {
    int xid = E_idx[b * 257 + t];
    int tgt = E_idx[b * 257 + t + 1];

    // ---- 1) gates partials: half0 = DWIH x prev_out, half1 = DWHH x h ----
    {
      int half = tau >> 9, j = tau & 511;
      const unsigned short* W = half ? DWHH : DWIH;
      const unsigned short* inb = half ? (const unsigned short*)inbf
                                       : (const unsigned short*)tobf;
      const uint4* wp = (const uint4*)W + j;
      float a0 = 0.f, a1 = 0.f, a2 = 0.f, a3 = 0.f;
      for (int k2 = 0; k2 < 256; ++k2) {
        uint4 w = wp[(size_t)k2 * 512];
        unsigned hp = *(const unsigned*)((const char*)inb + k2 * 4);
        a0 = dot2bf(w.x, hp, a0);
        a1 = dot2bf(w.y, hp, a1);
        a2 = dot2bf(w.z, hp, a2);
        a3 = dot2bf(w.w, hp, a3);
      }
      *(float4*)&part[half][j][0] = make_float4(a0, a1, a2, a3);
    }
    __syncthreads();
    // ---- 2) combine -> h, c ----
    if (tau < 512) {
      int j = tau;
      float4 p0 = *(const float4*)&part[0][j][0];
      float4 p1 = *(const float4*)&part[1][j][0];
      uint2 xg = *(const uint2*)(XDEC + ((size_t)xid * 512 + j) * 4);
      float g0 = p0.x + p1.x + db[j] + bfl(xg.x);
      float g1 = p0.y + p1.y + db[512 + j] + bfh(xg.x);
      float g2 = p0.z + p1.z + db[1024 + j] + bfl(xg.y);
      float g3 = p0.w + p1.w + db[1536 + j] + bfh(xg.y);
      float ig = sigm(g0), fg = sigm(g1), gg = tanhf(g2), og = sigm(g3);
      float c = fg * cst[j] + ig * gg;
      cst[j] = c;
      float h = og * tanhf(c);
      hf32[j] = h;
      inbf[j] = f2bf(h);
    }
    __syncthreads();
    // ---- 3) u = Wattn^T h ----
    {
      const uint2* wp = (const uint2*)WATT + tau;
      float au = 0.f;
      for (int i4 = 0; i4 < 128; ++i4) {
        uint2 w = wp[(size_t)i4 * 1024];
        uint2 hp = *(const uint2*)((const char*)inbf + i4 * 8);
        au = dot2bf(w.x, hp.x, au);
        au = dot2bf(w.y, hp.y, au);
      }
      ubf[tau] = f2bf(au);
    }
    __syncthreads();
    // ---- 4) scores: wave wv handles l = wv*16..+15, lanes span f ----
    {
      uint4 u0 = *(const uint4*)((const char*)ubf + lane * 16);
      uint4 u1 = *(const uint4*)((const char*)ubf + 1024 + lane * 16);
      for (int li = 0; li < 16; ++li) {
        int l = wv * 16 + li;
        const uint4* e0 = (const uint4*)(encB + (size_t)l * 1024) + lane;
        uint4 ea = e0[0];
        uint4 eb = e0[64];
        float s = 0.f;
        s = dot2bf(ea.x, u0.x, s); s = dot2bf(ea.y, u0.y, s);
        s = dot2bf(ea.z, u0.z, s); s = dot2bf(ea.w, u0.w, s);
        s = dot2bf(eb.x, u1.x, s); s = dot2bf(eb.y, u1.y, s);
        s = dot2bf(eb.z, u1.z, s); s = dot2bf(eb.w, u1.w, s);
        for (int o2 = 32; o2; o2 >>= 1) s += __shfl_xor(s, o2);
        if (lane == 0) sc[l] = s;
      }
    }
    __syncthreads();
    // ---- 5) softmax over 256 ----
    if (tau < 256) {
      float s = sc[tau];
      if (C_pad[b * 256 + tau]) s = -3.0e38f;
      sc[tau] = s;
      float m = s;
      for (int o2 = 32; o2; o2 >>= 1) m = fmaxf(m, __shfl_xor(m, o2));
      if (lane == 0) red[wv] = m;
    }
    __syncthreads();
    if (tau < 256) {
      float M = fmaxf(fmaxf(red[0], red[1]), fmaxf(red[2], red[3]));
      float e = expf(sc[tau] - M);
      pr[tau] = e;
      float sum = e;
      for (int o2 = 32; o2; o2 >>= 1) sum += __shfl_xor(sum, o2);
      if (lane == 0) red[4 + wv] = sum;
    }
    __syncthreads();
    if (tau < 256) {
      float D = red[4] + red[5] + red[6] + red[7];
      pr[tau] = pr[tau] / D;
    }
    __syncthreads();
    // ---- 6) ctx = sum_l p[l] * enc[l][:] ----
    if (tau < 512) {
      const unsigned short* ep = encB + tau * 2;
      float ax = 0.f, ay = 0.f;
      for (int l = 0; l < 256; ++l) {
        unsigned w = *(const unsigned*)(ep + (size_t)l * 1024);
        float p = pr[l];
        ax += p * bfl(w);
        ay += p * bfh(w);
      }
      ctxf[2 * tau] = ax;
      ctxf[2 * tau + 1] = ay;
      unsigned packed = (unsigned)f2bf(ax) | ((unsigned)f2bf(ay) << 16);
      *(unsigned*)&inbf[512 + 2 * tau] = packed;
    }
    __syncthreads();
    // ---- 7) p_gen ----
    {
      float acc = 0.f;
      if (tau < 512) {
        int j = tau;
        acc = hf32[j] * pgh[j] + cst[j] * pgcc[j] + bf2f(tobf[j]) * pgi[128 + j]
            + ctxf[j] * pgc[j] + ctxf[512 + j] * pgc[512 + j];
      }
      for (int o2 = 32; o2; o2 >>= 1) acc += __shfl_xor(acc, o2);
      if (lane == 0) red[wv] = acc;
    }
    __syncthreads();
    if (tau == 0) {
      float s = 0.f;
      for (int i = 0; i < 8; ++i) s += red[i];
      s += pgi[xid] + pgb[0];
      scal[0] = sigm(s);
    }
    __syncthreads();
    // ---- 8) t_out = tanh([h;ctx] @ Wout^T) ----
    {
      int half = tau >> 9, j = tau & 511;
      const uint2* wp = (const uint2*)WOUT + j;
      float a = 0.f;
      int i40 = half * 192;
      for (int i4 = 0; i4 < 192; ++i4) {
        uint2 w = wp[(size_t)(i40 + i4) * 512];
        uint2 ip = *(const uint2*)((const char*)inbf + (i40 + i4) * 8);
        a = dot2bf(w.x, ip.x, a);
        a = dot2bf(w.y, ip.y, a);
      }
      part[0][j][half] = a;
    }
    __syncthreads();
    if (tau < 512) {
      float tv = tanhf(part[0][tau][0] + part[0][tau][1]);
      tobf[tau] = f2bf(tv);
    }
    __syncthreads();
    // ---- 9) vocab logits ----
    {
      float* lgp = &part[0][0][0];   // [128][8]
      int v = tau >> 3, seg = tau & 7;
      const uint2* wp = (const uint2*)WVOC + v;
      float a = 0.f;
      for (int i4i = 0; i4i < 16; ++i4i) {
        int i4 = seg * 16 + i4i;
        uint2 w = wp[(size_t)i4 * 128];
        uint2 ip = *(const uint2*)((const char*)tobf + i4 * 8);
        a = dot2bf(w.x, ip.x, a);
        a = dot2bf(w.y, ip.y, a);
      }
      lgp[v * 8 + seg] = a;
    }
    __syncthreads();
    {
      float* lgp = &part[0][0][0];
      if (tau < 128) {
        float lg = 0.f;
        for (int s8 = 0; s8 < 8; ++s8) lg += lgp[tau * 8 + s8];
        lgf[tau] = lg;
        float m = lg;
        for (int o2 = 32; o2; o2 >>= 1) m = fmaxf(m, __shfl_xor(m, o2));
        if (lane == 0) red[8 + wv] = m;
      }
    }
    __syncthreads();
    if (tau < 128) {
      float mx = fmaxf(red[8], red[9]);
      float e = expf(lgf[tau] - mx);
      for (int o2 = 32; o2; o2 >>= 1) e += __shfl_xor(e, o2);
      if (lane == 0) red[10 + wv] = e;
      if (tau == 0) red[12] = mx;
    }
    __syncthreads();
    // ---- 10) copy mass + nll ----
    {
      float cm = 0.f;
      if (tau < 256 && C_idx[b * 256 + tau] == tgt) cm = pr[tau];
      for (int o2 = 32; o2; o2 >>= 1) cm += __shfl_xor(cm, o2);
      if (lane == 0 && wv < 4) red[wv] = cm;
    }
    __syncthreads();
    if (tau == 0) {
      float Pg = scal[0];
      float mx = red[12];
      float sume = red[10] + red[11];
      float gen_tgt = expf(lgf[tgt] - mx) / sume;
      float copy = (red[0] + red[1] + red[2] + red[3]) * (1.f - Pg);
      float prob = Pg * gen_tgt + copy;
      out[b * 256 + t] = (tgt == 0) ? 0.f : -logf(prob);
    }
    __syncthreads();
  }
}

// ======================= host =======================
extern "C" void kernel_launch(void* const* d_in, const int* in_sizes, int n_in,
                              void* d_out, int out_size, void* d_ws, size_t ws_size,
                              hipStream_t stream) {
  (void)in_sizes; (void)n_in; (void)out_size; (void)ws_size;
  const int* C_idx = (const int*)d_in[0];
  const int* E_idx = (const int*)d_in[1];
  const unsigned char* C_pad = (const unsigned char*)d_in[2];
  const float* eWihF = (const float*)d_in[3];
  const float* eWhhF = (const float*)d_in[4];
  const float* ebF   = (const float*)d_in[5];
  const float* eWihB = (const float*)d_in[6];
  const float* eWhhB = (const float*)d_in[7];
  const float* ebB   = (const float*)d_in[8];
  const float* dWih  = (const float*)d_in[9];
  const float* dWhh  = (const float*)d_in[10];
  const float* db    = (const float*)d_in[11];
  const float* Wh    = (const float*)d_in[12];
  const float* Wc    = (const float*)d_in[13];
  const float* Wattn = (const float*)d_in[14];
  const float* Wout  = (const float*)d_in[15];
  const float* Wvoc  = (const float*)d_in[16];
  const float* pgc   = (const float*)d_in[17];
  const float* pgi   = (const float*)d_in[18];
  const float* pgh   = (const float*)d_in[19];
  const float* pgcc  = (const float*)d_in[20];
  const float* pgb   = (const float*)d_in[21];
  char* wsb = (char*)d_ws;
  float* out = (float*)d_out;

  k_pre1<<<256, 256, 0, stream>>>(eWhhF, eWhhB, eWihF, eWihB, wsb);
  k_enc<<<256, 512, 0, stream>>>(ebF, ebB, C_idx, wsb);
  k_pre2<<<256, 256, 0, stream>>>(dWih, dWhh, Wattn, Wout, Wvoc, wsb);
  k_dec<<<128, 1024, 0, stream>>>(C_idx, E_idx, C_pad, db, Wh, Wc,
                                  pgc, pgi, pgh, pgcc, pgb, wsb, out);
}

// Round 4
// 27286.627 us; speedup vs baseline: 3.4583x; 2.3201x over previous
//
#include <hip/hip_runtime.h>

// ======================= ws layout (bytes) — stay <= 76,558,336 =======================
static constexpr size_t OFF_ENC   = 0;          // bf16 [128 b][256 l][1024 f] = 64 MiB
// ---- enc-phase overlay ----
static constexpr size_t OFF_WGE   = 67108864;   // bf16 [2dir][2048 row][512 k]   (4 MiB)
static constexpr size_t OFF_WIHTE = 71303168;   // bf16 [2dir][128 v][2048 row]   (1 MiB)
static constexpr size_t OFF_HENC  = 72351744;   // bf16 [2dir][2par][512][128]    (512 KiB)
static constexpr size_t OFF_CENC  = 72876032;   // f32  [2dir][512][128]          (512 KiB)
// ---- dec-phase overlay (pre2 runs AFTER h0c0; overwrites WGE/WIHTE/HENC/CENC) ----
static constexpr size_t OFF_WGATE = 67108864;   // bf16 [2048 row][1024 k]        (4 MiB)
static constexpr size_t OFF_XDEC  = 71303168;   // bf16 [128 v][2048 row]         (512 KiB)
static constexpr size_t OFF_WATTT = 71827456;   // bf16 [1024 i][512 o]           (1 MiB)
static constexpr size_t OFF_WOUT  = 72876032;   // bf16 [512 n][1536 k]           (1.5 MiB)
static constexpr size_t OFF_WVOCT = 74448896;   // uint [256 kk][128 v] bf16x2    (128 KiB)
// ---- persistent dec state ----
static constexpr size_t OFF_HDEC  = 74579968;   // bf16 paired [2 par][256 kk][128 b] (256 KiB)
static constexpr size_t OFF_CDEC  = 74842112;   // f32 [512][128]                 (256 KiB)
static constexpr size_t OFF_TOUT  = 75104256;   // bf16 paired [2 par][256 kk][128 b]
static constexpr size_t OFF_UFB   = 75366400;   // bf16 paired [512 kk][128 b]
static constexpr size_t OFF_CTXF  = 75628544;   // bf16 paired [512 kk][128 b]
static constexpr size_t OFF_CTXP  = 75890688;   // bf16 [2 ch][128 b][1024 f]     (512 KiB)
static constexpr size_t OFF_SC    = 76414976;   // bf16 [128 b][256 l]            (64 KiB)
static constexpr size_t OFF_MSP   = 76480512;   // f32 Mp[128][2] then Sp[128][2] (2 KiB)
static constexpr size_t OFF_MD    = 76482560;   // f32 M[128], D[128], PG[128]    (1.5 KiB)

// ======================= helpers =======================
__device__ __forceinline__ float sigm(float x) { return 1.f / (1.f + expf(-x)); }
__device__ __forceinline__ unsigned short f2bf(float f) {
  unsigned u = __float_as_uint(f);
  u += 0x7fffu + ((u >> 16) & 1u);
  return (unsigned short)(u >> 16);
}
__device__ __forceinline__ float bfl(unsigned w) { return __uint_as_float(w << 16); }
__device__ __forceinline__ float bfh(unsigned w) { return __uint_as_float(w & 0xffff0000u); }
__device__ __forceinline__ float bf2f(unsigned short v) { return __uint_as_float(((unsigned)v) << 16); }

#if defined(__has_builtin)
#if __has_builtin(__builtin_amdgcn_fdot2_f32_bf16)
#define HAVE_DOT2BF 1
#endif
#endif
#ifdef HAVE_DOT2BF
typedef __bf16 bf2_t __attribute__((ext_vector_type(2)));
__device__ __forceinline__ float dot2bf(unsigned w, unsigned h, float acc) {
  return __builtin_amdgcn_fdot2_f32_bf16(__builtin_bit_cast(bf2_t, w),
                                         __builtin_bit_cast(bf2_t, h), acc, false);
}
#else
__device__ __forceinline__ float dot2bf(unsigned w, unsigned h, float acc) {
  return acc + bfl(w) * bfl(h) + bfh(w) * bfh(h);
}
#endif

// ======================= pre1: encoder weights =======================
__global__ __launch_bounds__(256) void k_pre1(const float* __restrict__ WhhF,
                                              const float* __restrict__ WhhB,
                                              const float* __restrict__ WihF,
                                              const float* __restrict__ WihB,
                                              char* __restrict__ wsb) {
  unsigned short* WGE = (unsigned short*)(wsb + OFF_WGE);
  unsigned short* WIH = (unsigned short*)(wsb + OFF_WIHTE);
  int id = blockIdx.x * 256 + threadIdx.x, str = gridDim.x * 256;
  for (int x = id; x < 2 * 2048 * 512; x += str) {
    int dir = x >> 20, r = (x >> 9) & 2047, k = x & 511;
    const float* W = dir ? WhhB : WhhF;
    WGE[x] = f2bf(W[(size_t)r * 512 + k]);
  }
  for (int x = id; x < 2 * 128 * 2048; x += str) {
    int dir = x >> 18, v = (x >> 11) & 127, r = x & 2047;
    const float* W = dir ? WihB : WihF;
    WIH[x] = f2bf(W[(size_t)r * 128 + v]);
  }
}

// ======================= pre2: decoder weights =======================
__global__ __launch_bounds__(256) void k_pre2(const float* __restrict__ dWih,
                                              const float* __restrict__ dWhh,
                                              const float* __restrict__ Wattn,
                                              const float* __restrict__ Wout,
                                              const float* __restrict__ Wvoc,
                                              char* __restrict__ wsb) {
  unsigned short* WG = (unsigned short*)(wsb + OFF_WGATE);
  unsigned short* XD = (unsigned short*)(wsb + OFF_XDEC);
  unsigned short* WA = (unsigned short*)(wsb + OFF_WATTT);
  unsigned short* WO = (unsigned short*)(wsb + OFF_WOUT);
  unsigned*       WV = (unsigned*)(wsb + OFF_WVOCT);
  int id = blockIdx.x * 256 + threadIdx.x, str = gridDim.x * 256;
  for (int x = id; x < 2048 * 1024; x += str) {
    int r = x >> 10, k = x & 1023;
    float v = (k < 512) ? dWih[(size_t)r * 640 + 128 + k] : dWhh[(size_t)r * 512 + (k - 512)];
    WG[x] = f2bf(v);
  }
  for (int x = id; x < 128 * 2048; x += str) {
    int v = x >> 11, r = x & 2047;
    XD[x] = f2bf(dWih[(size_t)r * 640 + v]);
  }
  for (int x = id; x < 1024 * 512; x += str) {
    int i = x >> 9, o = x & 511;
    WA[x] = f2bf(Wattn[(size_t)o * 1024 + i]);
  }
  for (int x = id; x < 512 * 1536; x += str) WO[x] = f2bf(Wout[x]);
  for (int x = id; x < 256 * 128; x += str) {
    int kk = x >> 7, v = x & 127;
    unsigned lo = f2bf(Wvoc[(size_t)v * 512 + 2 * kk]);
    unsigned hi = f2bf(Wvoc[(size_t)v * 512 + 2 * kk + 1]);
    WV[x] = lo | (hi << 16);
  }
}

// ======================= encoder step (grid 256 x 512) =======================
__global__ __launch_bounds__(512) void k_encs(const float* __restrict__ bF,
                                              const float* __restrict__ bB,
                                              const int* __restrict__ C_idx,
                                              char* __restrict__ wsb, int t) {
  int tau = threadIdx.x, bid = blockIdx.x;
  int b = tau & 127, slot = tau >> 7;
  int dir = bid >> 7;
  int j = __builtin_amdgcn_readfirstlane(((bid & 127) << 2) + slot);
  int dd = __builtin_amdgcn_readfirstlane(dir);
  int rp = t & 1, wp = rp ^ 1;
  const unsigned* inw = (const unsigned*)(wsb + OFF_HENC) + ((size_t)(dd * 2 + rp) * 256) * 128 + b;
  const uint4* w0 = (const uint4*)((const unsigned*)(wsb + OFF_WGE) + ((size_t)dd * 2048 + j) * 256);
  const uint4* w1 = (const uint4*)((const unsigned*)(wsb + OFF_WGE) + ((size_t)dd * 2048 + 512 + j) * 256);
  const uint4* w2 = (const uint4*)((const unsigned*)(wsb + OFF_WGE) + ((size_t)dd * 2048 + 1024 + j) * 256);
  const uint4* w3 = (const uint4*)((const unsigned*)(wsb + OFF_WGE) + ((size_t)dd * 2048 + 1536 + j) * 256);
  int l = dd ? (255 - t) : t;
  int cidx = C_idx[b * 256 + l];
  const unsigned short* xg = (const unsigned short*)(wsb + OFF_WIHTE) + ((size_t)dd * 128 + cidx) * 2048;
  const float* bias = dd ? bB : bF;
  float a0 = bias[j] + bf2f(xg[j]);
  float a1 = bias[512 + j] + bf2f(xg[512 + j]);
  float a2 = bias[1024 + j] + bf2f(xg[1024 + j]);
  float a3 = bias[1536 + j] + bf2f(xg[1536 + j]);
#pragma unroll 4
  for (int q = 0; q < 64; ++q) {
    uint4 W0 = w0[q], W1 = w1[q], W2 = w2[q], W3 = w3[q];
    unsigned i0 = inw[(q * 4 + 0) * 128], i1 = inw[(q * 4 + 1) * 128];
    unsigned i2 = inw[(q * 4 + 2) * 128], i3 = inw[(q * 4 + 3) * 128];
    a0 = dot2bf(W0.x, i0, a0); a0 = dot2bf(W0.y, i1, a0); a0 = dot2bf(W0.z, i2, a0); a0 = dot2bf(W0.w, i3, a0);
    a1 = dot2bf(W1.x, i0, a1); a1 = dot2bf(W1.y, i1, a1); a1 = dot2bf(W1.z, i2, a1); a1 = dot2bf(W1.w, i3, a1);
    a2 = dot2bf(W2.x, i0, a2); a2 = dot2bf(W2.y, i1, a2); a2 = dot2bf(W2.z, i2, a2); a2 = dot2bf(W2.w, i3, a2);
    a3 = dot2bf(W3.x, i0, a3); a3 = dot2bf(W3.y, i1, a3); a3 = dot2bf(W3.z, i2, a3); a3 = dot2bf(W3.w, i3, a3);
  }
  float ig = sigm(a0), fg = sigm(a1), gg = tanhf(a2), og = sigm(a3);
  float* cp = (float*)(wsb + OFF_CENC) + ((size_t)dir * 512 + j) * 128 + b;
  float c = fg * (*cp) + ig * gg;
  *cp = c;
  float h = og * tanhf(c);
  unsigned short hb = f2bf(h);
  ((unsigned short*)(wsb + OFF_HENC))[((((size_t)(dir * 2 + wp) * 256) + (j >> 1)) * 128 + b) * 2 + (j & 1)] = hb;
  ((unsigned short*)(wsb + OFF_ENC))[((size_t)b * 256 + l) * 1024 + dir * 512 + j] = hb;
}

// ======================= h0/c0 (grid 256 x 512) =======================
__global__ __launch_bounds__(512) void k_h0(const float* __restrict__ Wh,
                                            const float* __restrict__ Wc,
                                            char* __restrict__ wsb) {
  int tau = threadIdx.x;
  int b = tau & 127, slot = tau >> 7;
  int row = __builtin_amdgcn_readfirstlane(blockIdx.x * 4 + slot);
  int sel = row >> 9, j = row & 511;
  const float* W = (sel ? Wc : Wh) + (size_t)j * 1024;
  const unsigned short* HE = (const unsigned short*)(wsb + OFF_HENC);
  const float* CE = (const float*)(wsb + OFF_CENC);
  float acc = 0.f;
  for (int k = 0; k < 1024; ++k) {
    int dir = k >> 9, k5 = k & 511;
    float in;
    if (sel == 0)
      in = bf2f(HE[((((size_t)(dir * 2 + 0) * 256) + (k5 >> 1)) * 128 + b) * 2 + (k5 & 1)]);
    else
      in = CE[((size_t)dir * 512 + k5) * 128 + b];
    acc += W[k] * in;
  }
  if (sel == 0)
    ((unsigned short*)(wsb + OFF_HDEC))[(((size_t)(j >> 1)) * 128 + b) * 2 + (j & 1)] = f2bf(acc);
  else
    ((float*)(wsb + OFF_CDEC))[(size_t)j * 128 + b] = acc;
}

// ======================= K1: gates (grid 256 x 512) =======================
__global__ __launch_bounds__(512) void k_gates(const int* __restrict__ E_idx,
                                               const float* __restrict__ db,
                                               char* __restrict__ wsb, int t) {
  __shared__ float part[2][4][128];
  int tau = threadIdx.x;
  int b = tau & 127, jslot = (tau >> 7) & 1, kh = tau >> 8;
  int j = __builtin_amdgcn_readfirstlane(blockIdx.x * 2 + jslot);
  int rp = t & 1, np = rp ^ 1;
  const unsigned* inw = (const unsigned*)(wsb + (kh ? OFF_HDEC : OFF_TOUT)) + (size_t)(kh ? np * 0 + rp : rp) * 256 * 128 + b;
  // kh=0: prev_out pairs (TOUT[rp]); kh=1: h pairs (HDEC[rp])
  const unsigned* WG = (const unsigned*)(wsb + OFF_WGATE);
  const uint4* w0 = (const uint4*)(WG + ((size_t)(0 * 512 + j)) * 512 + kh * 256);
  const uint4* w1 = (const uint4*)(WG + ((size_t)(1 * 512 + j)) * 512 + kh * 256);
  const uint4* w2 = (const uint4*)(WG + ((size_t)(2 * 512 + j)) * 512 + kh * 256);
  const uint4* w3 = (const uint4*)(WG + ((size_t)(3 * 512 + j)) * 512 + kh * 256);
  float a0 = 0.f, a1 = 0.f, a2 = 0.f, a3 = 0.f;
#pragma unroll 4
  for (int q = 0; q < 64; ++q) {
    uint4 W0 = w0[q], W1 = w1[q], W2 = w2[q], W3 = w3[q];
    unsigned i0 = inw[(q * 4 + 0) * 128], i1 = inw[(q * 4 + 1) * 128];
    unsigned i2 = inw[(q * 4 + 2) * 128], i3 = inw[(q * 4 + 3) * 128];
    a0 = dot2bf(W0.x, i0, a0); a0 = dot2bf(W0.y, i1, a0); a0 = dot2bf(W0.z, i2, a0); a0 = dot2bf(W0.w, i3, a0);
    a1 = dot2bf(W1.x, i0, a1); a1 = dot2bf(W1.y, i1, a1); a1 = dot2bf(W1.z, i2, a1); a1 = dot2bf(W1.w, i3, a1);
    a2 = dot2bf(W2.x, i0, a2); a2 = dot2bf(W2.y, i1, a2); a2 = dot2bf(W2.z, i2, a2); a2 = dot2bf(W2.w, i3, a2);
    a3 = dot2bf(W3.x, i0, a3); a3 = dot2bf(W3.y, i1, a3); a3 = dot2bf(W3.z, i2, a3); a3 = dot2bf(W3.w, i3, a3);
  }
  if (kh == 1) { part[jslot][0][b] = a0; part[jslot][1][b] = a1; part[jslot][2][b] = a2; part[jslot][3][b] = a3; }
  __syncthreads();
  if (kh == 0) {
    int xid = E_idx[b * 257 + t];
    const unsigned short* xg = (const unsigned short*)(wsb + OFF_XDEC) + (size_t)xid * 2048;
    float g0 = a0 + part[jslot][0][b] + db[j] + bf2f(xg[j]);
    float g1 = a1 + part[jslot][1][b] + db[512 + j] + bf2f(xg[512 + j]);
    float g2 = a2 + part[jslot][2][b] + db[1024 + j] + bf2f(xg[1024 + j]);
    float g3 = a3 + part[jslot][3][b] + db[1536 + j] + bf2f(xg[1536 + j]);
    float ig = sigm(g0), fg = sigm(g1), gg = tanhf(g2), og = sigm(g3);
    float* cp = (float*)(wsb + OFF_CDEC) + (size_t)j * 128 + b;
    float c = fg * (*cp) + ig * gg;
    *cp = c;
    float h = og * tanhf(c);
    ((unsigned short*)(wsb + OFF_HDEC))[(((size_t)np * 256 + (j >> 1)) * 128 + b) * 2 + (j & 1)] = f2bf(h);
  }
}

// ======================= K2: u = Wattn^T h (grid 256 x 512) =======================
__global__ __launch_bounds__(512) void k_u(char* __restrict__ wsb, int t) {
  int tau = threadIdx.x;
  int b = tau & 127, slot = tau >> 7;
  int i = __builtin_amdgcn_readfirstlane(blockIdx.x * 4 + slot);
  int np = (t & 1) ^ 1;
  const unsigned* inw = (const unsigned*)(wsb + OFF_HDEC) + (size_t)np * 256 * 128 + b;
  const uint4* w = (const uint4*)((const unsigned*)(wsb + OFF_WATTT) + (size_t)i * 256);
  float a = 0.f;
#pragma unroll 4
  for (int q = 0; q < 64; ++q) {
    uint4 W = w[q];
    a = dot2bf(W.x, inw[(q * 4 + 0) * 128], a);
    a = dot2bf(W.y, inw[(q * 4 + 1) * 128], a);
    a = dot2bf(W.z, inw[(q * 4 + 2) * 128], a);
    a = dot2bf(W.w, inw[(q * 4 + 3) * 128], a);
  }
  ((unsigned short*)(wsb + OFF_UFB))[(((size_t)(i >> 1)) * 128 + b) * 2 + (i & 1)] = f2bf(a);
}

// ======================= K3: flash attn chunk (grid 256 x 256) =======================
__global__ __launch_bounds__(256) void k_attn(const unsigned char* __restrict__ C_pad,
                                              char* __restrict__ wsb) {
  __shared__ __align__(16) unsigned short tile[32][1024];  // 64 KiB
  __shared__ __align__(16) unsigned ulds[512];
  __shared__ float sc_l[32];
  __shared__ float p_l[32];
  __shared__ float red[4];
  int bid = blockIdx.x, tau = threadIdx.x;
  int b = bid >> 1, ch = bid & 1;
  int lane = tau & 63, wv = tau >> 6;
  const unsigned* UW = (const unsigned*)(wsb + OFF_UFB) + b;
  ulds[tau] = UW[(size_t)tau * 128];
  ulds[tau + 256] = UW[(size_t)(tau + 256) * 128];
  float mold = -3.0e38f, ssum = 0.f;
  float acc0 = 0.f, acc1 = 0.f, acc2 = 0.f, acc3 = 0.f;
  unsigned short* SCp = (unsigned short*)(wsb + OFF_SC) + (size_t)b * 256;
  int L0 = ch * 128;
  for (int sub = 0; sub < 4; ++sub) {
    const uint4* src = (const uint4*)((const unsigned short*)wsb + ((size_t)b * 256 + L0 + sub * 32) * 1024);
    __syncthreads();
#pragma unroll
    for (int it = 0; it < 16; ++it) ((uint4*)tile)[it * 256 + tau] = src[it * 256 + tau];
    __syncthreads();
    // scores: wave wv handles rows wv*8..+7, lanes span f (16 each)
    const uint4* t4 = (const uint4*)tile;
    const uint4* u4 = (const uint4*)ulds;
#pragma unroll
    for (int li = 0; li < 8; ++li) {
      int l = wv * 8 + li;
      uint4 ea = t4[l * 128 + lane * 2];
      uint4 eb = t4[l * 128 + lane * 2 + 1];
      uint4 ua = u4[lane * 2];
      uint4 ub = u4[lane * 2 + 1];
      float s = 0.f;
      s = dot2bf(ea.x, ua.x, s); s = dot2bf(ea.y, ua.y, s);
      s = dot2bf(ea.z, ua.z, s); s = dot2bf(ea.w, ua.w, s);
      s = dot2bf(eb.x, ub.x, s); s = dot2bf(eb.y, ub.y, s);
      s = dot2bf(eb.z, ub.z, s); s = dot2bf(eb.w, ub.w, s);
      for (int o = 32; o; o >>= 1) s += __shfl_xor(s, o);
      if (lane == 0) {
        int gl = L0 + sub * 32 + l;
        if (C_pad[b * 256 + gl]) s = -3.0e38f;
        sc_l[l] = s;
        SCp[gl] = f2bf(s);
      }
    }
    __syncthreads();
    if (tau < 64) {
      float v = (tau < 32) ? sc_l[tau] : -3.0e38f;
      for (int o = 32; o; o >>= 1) v = fmaxf(v, __shfl_xor(v, o));
      if (tau == 0) red[0] = v;
    }
    __syncthreads();
    float mnew = fmaxf(mold, red[0]);
    float r = expf(mold - mnew);
    if (tau < 64) {
      float pv = (tau < 32) ? expf(sc_l[tau] - mnew) : 0.f;
      if (tau < 32) p_l[tau] = pv;
      for (int o = 32; o; o >>= 1) pv += __shfl_xor(pv, o);
      if (tau == 0) red[1] = pv;
    }
    __syncthreads();
    ssum = ssum * r + red[1];
    mold = mnew;
    acc0 *= r; acc1 *= r; acc2 *= r; acc3 *= r;
    const uint2* t2 = (const uint2*)tile;
#pragma unroll 8
    for (int l = 0; l < 32; ++l) {
      float pv = p_l[l];
      uint2 ev = t2[l * 256 + tau];
      acc0 += pv * bfl(ev.x); acc1 += pv * bfh(ev.x);
      acc2 += pv * bfl(ev.y); acc3 += pv * bfh(ev.y);
    }
  }
  // write partials
  unsigned* CP = (unsigned*)(wsb + OFF_CTXP);
  unsigned wlo = (unsigned)f2bf(acc0) | ((unsigned)f2bf(acc1) << 16);
  unsigned whi = (unsigned)f2bf(acc2) | ((unsigned)f2bf(acc3) << 16);
  CP[(((size_t)ch * 128 + b) * 1024 + tau * 4) >> 1] = wlo;
  CP[((((size_t)ch * 128 + b) * 1024 + tau * 4) >> 1) + 1] = whi;
  if (tau == 0) {
    float* MSP = (float*)(wsb + OFF_MSP);
    MSP[b * 2 + ch] = mold;
    MSP[256 + b * 2 + ch] = ssum;
  }
}

// ======================= K4: combine + pgen (grid 128 x 256) =======================
__global__ __launch_bounds__(256) void k_comb(const int* __restrict__ E_idx,
                                              const float* __restrict__ pgc,
                                              const float* __restrict__ pgi,
                                              const float* __restrict__ pgh,
                                              const float* __restrict__ pgcc,
                                              const float* __restrict__ pgb,
                                              char* __restrict__ wsb, int t) {
  __shared__ float red[4];
  int b = blockIdx.x, tau = threadIdx.x;
  int lane = tau & 63, wv = tau >> 6;
  int rp = t & 1, np = rp ^ 1;
  const float* MSP = (const float*)(wsb + OFF_MSP);
  float m0 = MSP[b * 2], m1 = MSP[b * 2 + 1];
  float s0 = MSP[256 + b * 2], s1 = MSP[256 + b * 2 + 1];
  float M = fmaxf(m0, m1);
  float e0 = expf(m0 - M), e1 = expf(m1 - M);
  float D = s0 * e0 + s1 * e1;
  float invD = 1.f / D;
  const unsigned* CP = (const unsigned*)(wsb + OFF_CTXP);
  size_t base0 = (((size_t)0 * 128 + b) * 1024 + tau * 4) >> 1;
  size_t base1 = (((size_t)1 * 128 + b) * 1024 + tau * 4) >> 1;
  unsigned c0l = CP[base0], c0h = CP[base0 + 1], c1l = CP[base1], c1h = CP[base1 + 1];
  float x0 = (bfl(c0l) * e0 + bfl(c1l) * e1) * invD;
  float x1 = (bfh(c0l) * e0 + bfh(c1l) * e1) * invD;
  float x2 = (bfl(c0h) * e0 + bfl(c1h) * e1) * invD;
  float x3 = (bfh(c0h) * e0 + bfh(c1h) * e1) * invD;
  unsigned* CF = (unsigned*)(wsb + OFF_CTXF);
  CF[((size_t)tau * 2) * 128 + b]     = (unsigned)f2bf(x0) | ((unsigned)f2bf(x1) << 16);
  CF[((size_t)tau * 2 + 1) * 128 + b] = (unsigned)f2bf(x2) | ((unsigned)f2bf(x3) << 16);
  int f0 = tau * 4;
  float pp = x0 * pgc[f0] + x1 * pgc[f0 + 1] + x2 * pgc[f0 + 2] + x3 * pgc[f0 + 3];
  if (f0 < 512) {
    const unsigned short* H = (const unsigned short*)(wsb + OFF_HDEC);
    const unsigned short* TO = (const unsigned short*)(wsb + OFF_TOUT);
    const float* C = (const float*)(wsb + OFF_CDEC);
#pragma unroll
    for (int e = 0; e < 4; ++e) {
      int f = f0 + e;
      float hv = bf2f(H[(((size_t)np * 256 + (f >> 1)) * 128 + b) * 2 + (f & 1)]);
      float pv = bf2f(TO[(((size_t)rp * 256 + (f >> 1)) * 128 + b) * 2 + (f & 1)]);
      float cv = C[(size_t)f * 128 + b];
      pp += hv * pgh[f] + cv * pgcc[f] + pv * pgi[128 + f];
    }
  }
  for (int o = 32; o; o >>= 1) pp += __shfl_xor(pp, o);
  if (lane == 0) red[wv] = pp;
  __syncthreads();
  if (tau == 0) {
    int xid = E_idx[b * 257 + t];
    float s = red[0] + red[1] + red[2] + red[3] + pgi[xid] + pgb[0];
    float* MD = (float*)(wsb + OFF_MD);
    MD[b] = M;
    MD[128 + b] = D;
    MD[256 + b] = sigm(s);
  }
}

// ======================= K5: wout (grid 256 x 512) =======================
__global__ __launch_bounds__(512) void k_wout(char* __restrict__ wsb, int t) {
  __shared__ float part[2][128];
  int tau = threadIdx.x;
  int b = tau & 127, nslot = (tau >> 7) & 1, kh = tau >> 8;
  int n = __builtin_amdgcn_readfirstlane(blockIdx.x * 2 + nslot);
  int np = (t & 1) ^ 1;
  const unsigned* HW = (const unsigned*)(wsb + OFF_HDEC) + (size_t)np * 256 * 128 + b;
  const unsigned* CW = (const unsigned*)(wsb + OFF_CTXF) + b;
  const unsigned* w = (const unsigned*)(wsb + OFF_WOUT) + (size_t)n * 768 + kh * 384;
  float a = 0.f;
  int p0 = kh * 384;
#pragma unroll 4
  for (int q = 0; q < 96; ++q) {
    uint4 W = ((const uint4*)w)[q];
#pragma unroll
    for (int e = 0; e < 4; ++e) {
      int pp = p0 + q * 4 + e;
      unsigned in = (pp < 256) ? HW[(size_t)pp * 128] : CW[(size_t)(pp - 256) * 128];
      unsigned wv = (e == 0) ? W.x : (e == 1) ? W.y : (e == 2) ? W.z : W.w;
      a = dot2bf(wv, in, a);
    }
  }
  if (kh == 1) part[nslot][b] = a;
  __syncthreads();
  if (kh == 0) {
    float tv = tanhf(a + part[nslot][b]);
    ((unsigned short*)(wsb + OFF_TOUT))[(((size_t)np * 256 + (n >> 1)) * 128 + b) * 2 + (n & 1)] = f2bf(tv);
  }
}

// ======================= K6: vocab softmax + copy mass + nll (grid 128 x 256) =======================
__global__ __launch_bounds__(256) void k_fin(const int* __restrict__ C_idx,
                                             const int* __restrict__ E_idx,
                                             char* __restrict__ wsb,
                                             float* __restrict__ out, int t) {
  __shared__ unsigned to_pld[256];
  __shared__ float lgp[2][128];
  __shared__ float lgf[128];
  __shared__ float red[8];
  int b = blockIdx.x, tau = threadIdx.x;
  int lane = tau & 63, wv = tau >> 6;
  int np = (t & 1) ^ 1;
  const unsigned* TOW = (const unsigned*)(wsb + OFF_TOUT) + (size_t)np * 256 * 128 + b;
  to_pld[tau] = TOW[(size_t)tau * 128];
  __syncthreads();
  int v = tau & 127, kh = tau >> 7;
  const unsigned* WV = (const unsigned*)(wsb + OFF_WVOCT) + v;
  float a = 0.f;
#pragma unroll 8
  for (int kkk = 0; kkk < 128; ++kkk) {
    int kk = kh * 128 + kkk;
    a = dot2bf(WV[(size_t)kk * 128], to_pld[kk], a);
  }
  lgp[kh][v] = a;
  __syncthreads();
  if (tau < 128) {
    float lg = lgp[0][tau] + lgp[1][tau];
    lgf[tau] = lg;
    float m = lg;
    for (int o = 32; o; o >>= 1) m = fmaxf(m, __shfl_xor(m, o));
    if (lane == 0) red[wv] = m;
  }
  __syncthreads();
  float mx = fmaxf(red[0], red[1]);
  if (tau < 128) {
    float e = expf(lgf[tau] - mx);
    for (int o = 32; o; o >>= 1) e += __shfl_xor(e, o);
    if (lane == 0) red[2 + wv] = e;
  }
  __syncthreads();
  const float* MD = (const float*)(wsb + OFF_MD);
  float M = MD[b], D = MD[128 + b], pg = MD[256 + b];
  int tgt = E_idx[b * 257 + t + 1];
  float cm = 0.f;
  {
    float s = bf2f(((const unsigned short*)(wsb + OFF_SC))[(size_t)b * 256 + tau]);
    if (C_idx[b * 256 + tau] == tgt) cm = expf(s - M);
  }
  for (int o = 32; o; o >>= 1) cm += __shfl_xor(cm, o);
  if (lane == 0) red[4 + wv] = cm;
  __syncthreads();
  if (tau == 0) {
    float sume = red[2] + red[3];
    float copy_raw = red[4] + red[5] + red[6] + red[7];
    float gen_tgt = expf(lgf[tgt] - mx) / sume;
    float prob = pg * gen_tgt + (1.f - pg) * copy_raw / D;
    out[b * 256 + t] = (tgt == 0) ? 0.f : -logf(prob);
  }
}

// ======================= host =======================
extern "C" void kernel_launch(void* const* d_in, const int* in_sizes, int n_in,
                              void* d_out, int out_size, void* d_ws, size_t ws_size,
                              hipStream_t stream) {
  (void)in_sizes; (void)n_in; (void)out_size; (void)ws_size;
  const int* C_idx = (const int*)d_in[0];
  const int* E_idx = (const int*)d_in[1];
  const unsigned char* C_pad = (const unsigned char*)d_in[2];
  const float* eWihF = (const float*)d_in[3];
  const float* eWhhF = (const float*)d_in[4];
  const float* ebF   = (const float*)d_in[5];
  const float* eWihB = (const float*)d_in[6];
  const float* eWhhB = (const float*)d_in[7];
  const float* ebB   = (const float*)d_in[8];
  const float* dWih  = (const float*)d_in[9];
  const float* dWhh  = (const float*)d_in[10];
  const float* db    = (const float*)d_in[11];
  const float* Wh    = (const float*)d_in[12];
  const float* Wc    = (const float*)d_in[13];
  const float* Wattn = (const float*)d_in[14];
  const float* Wout  = (const float*)d_in[15];
  const float* Wvoc  = (const float*)d_in[16];
  const float* pgc   = (const float*)d_in[17];
  const float* pgi   = (const float*)d_in[18];
  const float* pgh   = (const float*)d_in[19];
  const float* pgcc  = (const float*)d_in[20];
  const float* pgb   = (const float*)d_in[21];
  char* wsb = (char*)d_ws;
  float* out = (float*)d_out;

  hipMemsetAsync(wsb + OFF_HENC, 0, 524288, stream);   // enc h state (both parities)
  hipMemsetAsync(wsb + OFF_CENC, 0, 524288, stream);   // enc c state
  hipMemsetAsync(wsb + OFF_TOUT, 0, 262144, stream);   // prev_out parity 0

  k_pre1<<<256, 256, 0, stream>>>(eWhhF, eWhhB, eWihF, eWihB, wsb);
  for (int t = 0; t < 256; ++t)
    k_encs<<<256, 512, 0, stream>>>(ebF, ebB, C_idx, wsb, t);
  k_h0<<<256, 512, 0, stream>>>(Wh, Wc, wsb);
  k_pre2<<<256, 256, 0, stream>>>(dWih, dWhh, Wattn, Wout, Wvoc, wsb);
  for (int t = 0; t < 256; ++t) {
    k_gates<<<256, 512, 0, stream>>>(E_idx, db, wsb, t);
    k_u<<<256, 512, 0, stream>>>(wsb, t);
    k_attn<<<256, 256, 0, stream>>>(C_pad, wsb);
    k_comb<<<128, 256, 0, stream>>>(E_idx, pgc, pgi, pgh, pgcc, pgb, wsb, t);
    k_wout<<<256, 512, 0, stream>>>(wsb, t);
    k_fin<<<128, 256, 0, stream>>>(C_idx, E_idx, wsb, out, t);
  }
}